// Round 1
// baseline (1460.034 us; speedup 1.0000x reference)
//
#include <hip/hip_runtime.h>
#include <math.h>

typedef __bf16 bf16x8 __attribute__((ext_vector_type(8)));
typedef float f32x4 __attribute__((ext_vector_type(4)));
typedef unsigned short u16;

#define DI __device__ __forceinline__

DI u16 f2bf(float f) {
  union { float f; unsigned u; } v; v.f = f;
  unsigned r = v.u + 0x7FFFu + ((v.u >> 16) & 1u);  // RNE
  return (u16)(r >> 16);
}

DI void gload_lds16(const u16* g, u16* l) {
  // dest = wave-uniform base + lane*16B (HW semantics); src is per-lane.
  __builtin_amdgcn_global_load_lds(
      (const __attribute__((address_space(1))) unsigned int*)g,
      (__attribute__((address_space(3))) unsigned int*)l, 16, 0, 0);
}

// ---------------- one-hot rows (l=0 of each section) --------------------
__global__ __launch_bounds__(256) void onehot_k(const int* __restrict__ x,
                                                float* __restrict__ out) {
  int bs = blockIdx.x;            // s*64 + b
  int s = bs >> 6, b = bs & 63;
  long base = ((long)b * 96 + s * 32) * 32000;
  float4* o4 = (float4*)(out + base);
  float4 z; z.x = z.y = z.z = z.w = 0.f;
  for (int i = threadIdx.x; i < 8000; i += 256) o4[i] = z;
  __syncthreads();
  if (threadIdx.x == 0) {
    int tok = x[b * 128 + (s + 1) * 32];
    out[base + tok] = 1.0f;
  }
}

// ---------------- CSM: mean-pool + W_csm + tanh -> sent[s][b][h] --------
__global__ __launch_bounds__(256) void sent_k(const int* __restrict__ x,
    const float* __restrict__ emb, const float* __restrict__ Wcsm,
    float* __restrict__ sent) {
  int bs = blockIdx.x; int s = bs >> 6, b = bs & 63;
  __shared__ float mean[512];
  int t = threadIdx.x;
  float a0 = 0.f, a1 = 0.f;
  for (int lt = 0; lt < 32; ++lt) {
    int tok = x[b * 128 + s * 32 + lt];
    const float* e = emb + (long)tok * 512;
    a0 += e[t]; a1 += e[t + 256];
  }
  mean[t] = a0 * (1.f / 32.f); mean[t + 256] = a1 * (1.f / 32.f);
  __syncthreads();
  float acc[4] = {0.f, 0.f, 0.f, 0.f};
  for (int e = 0; e < 512; ++e) {
    float mv = mean[e];
    const float* wr_ = Wcsm + (long)e * 1024 + t;
#pragma unroll
    for (int j = 0; j < 4; ++j) acc[j] += mv * wr_[j * 256];
  }
#pragma unroll
  for (int j = 0; j < 4; ++j)
    sent[(long)bs * 1024 + t + j * 256] = tanhf(acc[j]);
}

// ---------------- RNN step: hout = tanh(x@Wx + h@Wh) --------------------
__global__ __launch_bounds__(256) void rnn_step_k(
    const float* __restrict__ xin, const float* __restrict__ hin,
    const float* __restrict__ Wx, const float* __restrict__ Wh,
    float* __restrict__ hout, u16* __restrict__ hsb, int useH) {
  int b = blockIdx.x >> 2, chunk = blockIdx.x & 3;
  int t = threadIdx.x;
  int h = chunk * 256 + t;
  __shared__ float xs[1024], hs_[1024];
#pragma unroll
  for (int i = 0; i < 4; ++i) {
    xs[t + 256 * i] = xin[b * 1024 + t + 256 * i];
    hs_[t + 256 * i] = useH ? hin[b * 1024 + t + 256 * i] : 0.f;
  }
  __syncthreads();
  float a0 = 0.f, a1 = 0.f, a2 = 0.f, a3 = 0.f;
  for (int k = 0; k < 1024; k += 4) {
    a0 += xs[k    ] * Wx[(long)(k    ) * 1024 + h] + hs_[k    ] * Wh[(long)(k    ) * 1024 + h];
    a1 += xs[k + 1] * Wx[(long)(k + 1) * 1024 + h] + hs_[k + 1] * Wh[(long)(k + 1) * 1024 + h];
    a2 += xs[k + 2] * Wx[(long)(k + 2) * 1024 + h] + hs_[k + 2] * Wh[(long)(k + 2) * 1024 + h];
    a3 += xs[k + 3] * Wx[(long)(k + 3) * 1024 + h] + hs_[k + 3] * Wh[(long)(k + 3) * 1024 + h];
  }
  float v = tanhf(a0 + a1 + a2 + a3);
  hout[b * 1024 + h] = v;
  if (hsb) hsb[b * 1024 + h] = f2bf(v);
}

// ---------------- transpose + fp32->bf16 : out[c][r] = bf16(in[r][c]) ---
__global__ __launch_bounds__(256) void transpose_cvt(
    const float* __restrict__ in, u16* __restrict__ out, int R, int C) {
  long zoff = (long)blockIdx.z * R * C;
  in += zoff; out += zoff;
  __shared__ float tile[32][33];
  int c0 = blockIdx.x * 32, r0 = blockIdx.y * 32;
  int tx = threadIdx.x & 31, ty = threadIdx.x >> 5;
#pragma unroll
  for (int i = 0; i < 4; ++i)
    tile[ty + 8 * i][tx] = in[(long)(r0 + ty + 8 * i) * C + c0 + tx];
  __syncthreads();
#pragma unroll
  for (int i = 0; i < 4; ++i)
    out[(long)(c0 + ty + 8 * i) * R + r0 + tx] = f2bf(tile[tx][ty + 8 * i]);
}

// ---------------- bf16 MFMA GEMM, 128x128 tile, BK=32, K=1024 -----------
// A: bf16 [M][1024] (MODE1: rows remapped r -> (r/31)*32 + r%31 + 1)
// Bt: bf16 [N][1024] (pre-transposed so K is contiguous)
// MODE 0: ctx  = tanh(hs @ U[mz])        -> bf16 ctx[(r*32+mz)*1024+col]
// MODE 1: cur  = tanh(acc + Ww[idx][col])-> bf16 cur[r*1024+col]
// MODE 2: ysec = acc                     -> f32 d_out scattered rows
template <int MODE>
__global__ __launch_bounds__(256) void gemm_bf16(
    const u16* __restrict__ A, const u16* __restrict__ Bt,
    const float* __restrict__ Ww, const int* __restrict__ xtok,
    void* __restrict__ outp, int M) {
  int mt, nt, mz = 0;
  if constexpr (MODE == 2) {
    // XCD-bijective chunking (12288 = 8*1536) + 8x8 tile groups for L2 reuse
    int flat = blockIdx.x;
    int wg = (flat & 7) * 1536 + (flat >> 3);
    int g = wg >> 6, w64 = wg & 63;
    mt = (g % 6) * 8 + (w64 & 7);
    nt = (g / 6) * 8 + (w64 >> 3);
    if (mt >= 47 || nt >= 250) return;
  } else {
    mt = blockIdx.x; nt = blockIdx.y; mz = blockIdx.z;
  }
  if constexpr (MODE == 0) Bt += (long)mz << 20;  // U slice [1024][1024]

  __shared__ __align__(16) u16 As[128 * 32];
  __shared__ __align__(16) u16 Bs[128 * 32];

  const int t = threadIdx.x;
  const int w = t >> 6, l = t & 63;
  const int lr = l & 15, lg = l >> 4;
  const int wr = w >> 1, wc = w & 1;

  int ar0 = mt * 128 + (t >> 2);
  int ar1 = ar0 + 64;
  if (ar0 >= M) ar0 = 0;
  if (ar1 >= M) ar1 = 0;
  long arow0, arow1;
  if constexpr (MODE == 1) {
    arow0 = (long)(ar0 / 31) * 32 + (ar0 % 31) + 1;
    arow1 = (long)(ar1 / 31) * 32 + (ar1 % 31) + 1;
  } else {
    arow0 = ar0; arow1 = ar1;
  }

  const u16* ga0 = A + arow0 * 1024 + (t & 3) * 8;
  const u16* ga1 = A + arow1 * 1024 + (t & 3) * 8;
  const u16* gb0 = Bt + ((long)nt * 128 + (t >> 2)) * 1024 + (t & 3) * 8;
  const u16* gb1 = gb0 + 64 * 1024;

  u16* dA0 = As + w * 512; u16* dA1 = As + 2048 + w * 512;
  u16* dB0 = Bs + w * 512; u16* dB1 = Bs + 2048 + w * 512;

  f32x4 acc[4][4] = {};

  for (int kt = 0; kt < 32; ++kt) {
    __syncthreads();
    gload_lds16(ga0, dA0); gload_lds16(ga1, dA1);
    gload_lds16(gb0, dB0); gload_lds16(gb1, dB1);
    ga0 += 32; ga1 += 32; gb0 += 32; gb1 += 32;
    __syncthreads();
    bf16x8 a[4], b[4];
#pragma unroll
    for (int m = 0; m < 4; ++m)
      a[m] = *(const bf16x8*)&As[(wr * 64 + m * 16 + lr) * 32 + lg * 8];
#pragma unroll
    for (int n = 0; n < 4; ++n)
      b[n] = *(const bf16x8*)&Bs[(wc * 64 + n * 16 + lr) * 32 + lg * 8];
#pragma unroll
    for (int m = 0; m < 4; ++m)
#pragma unroll
      for (int n = 0; n < 4; ++n)
        acc[m][n] = __builtin_amdgcn_mfma_f32_16x16x32_bf16(a[m], b[n], acc[m][n], 0, 0, 0);
  }

#pragma unroll
  for (int m = 0; m < 4; ++m) {
#pragma unroll
    for (int j = 0; j < 4; ++j) {
      int r = mt * 128 + wr * 64 + m * 16 + lg * 4 + j;
      if (r >= M) continue;
      if constexpr (MODE == 0) {
        u16* oc = (u16*)outp;
#pragma unroll
        for (int n = 0; n < 4; ++n) {
          int col = nt * 128 + wc * 64 + n * 16 + lr;
          oc[((long)r * 32 + mz) * 1024 + col] = f2bf(tanhf(acc[m][n][j]));
        }
      } else if constexpr (MODE == 1) {
        int sb = r / 31, l1 = r % 31;
        int s = sb >> 6, b = sb & 63;
        int widx = xtok[b * 128 + (s + 1) * 32 + l1];
        const float* wwr = Ww + (long)widx * 1024;
        u16* oc = (u16*)outp;
#pragma unroll
        for (int n = 0; n < 4; ++n) {
          int col = nt * 128 + wc * 64 + n * 16 + lr;
          oc[(long)r * 1024 + col] = f2bf(tanhf(acc[m][n][j] + wwr[col]));
        }
      } else {
        int s = r / 1984, rem = r % 1984;
        int b = rem / 31, l1 = rem % 31;
        float* o = (float*)outp + ((long)b * 96 + s * 32 + l1 + 1) * 32000;
#pragma unroll
        for (int n = 0; n < 4; ++n) {
          int col = nt * 128 + wc * 64 + n * 16 + lr;
          o[col] = acc[m][n][j];
        }
      }
    }
  }
}

// ------------------------------- launch ---------------------------------
extern "C" void kernel_launch(void* const* d_in, const int* in_sizes, int n_in,
                              void* d_out, int out_size, void* d_ws, size_t ws_size,
                              hipStream_t stream) {
  const int*   x    = (const int*)d_in[0];
  const float* emb  = (const float*)d_in[2];
  const float* Wcsm = (const float*)d_in[3];
  const float* Wx1  = (const float*)d_in[4];
  const float* Wh1  = (const float*)d_in[5];
  const float* Wx2  = (const float*)d_in[6];
  const float* Wh2  = (const float*)d_in[7];
  const float* U    = (const float*)d_in[8];
  const float* Ww   = (const float*)d_in[9];
  const float* Wc   = (const float*)d_in[10];
  const float* Wfc  = (const float*)d_in[11];
  float* out = (float*)d_out;

  // workspace carve (~96.2 MB): BIG is shared between U^T (stage C) and
  // Wfc^T (stage E) — lifetimes are stream-ordered disjoint.
  char* ws = (char*)d_ws;
  float* sent = (float*)(ws + 0);          //  786432 B  [3][64][1024] f32
  float* h1   = (float*)(ws + 786432);     //  524288 B  2x [64][1024]
  float* h2   = (float*)(ws + 1310720);    //  524288 B
  u16*   hsb  = (u16*)(ws + 1835008);      //  393216 B  [3][64][1024] bf16
  u16*   ctx  = (u16*)(ws + 2228224);      // 12582912 B [192][32][1024] bf16
  u16*   cur  = (u16*)(ws + 14811136);     // 12189696 B [5952][1024] bf16
  u16*   WcT  = (u16*)(ws + 27000832);     //  2097152 B [1024][1024] bf16
  u16*   BIG  = (u16*)(ws + 29097984);     // 67108864 B U^T then Wfc^T

  onehot_k<<<192, 256, 0, stream>>>(x, out);
  sent_k<<<192, 256, 0, stream>>>(x, emb, Wcsm, sent);

  // RNN: 3 sentences x (h1, h2); ping-pong buffers; hs[s] = h2 after step s
  rnn_step_k<<<256, 256, 0, stream>>>(sent,          h1,        Wx1, Wh1, h1,         nullptr,      0);
  rnn_step_k<<<256, 256, 0, stream>>>(h1,            h2,        Wx2, Wh2, h2,         hsb,          0);
  rnn_step_k<<<256, 256, 0, stream>>>(sent + 65536,  h1,        Wx1, Wh1, h1 + 65536, nullptr,      1);
  rnn_step_k<<<256, 256, 0, stream>>>(h1 + 65536,    h2,        Wx2, Wh2, h2 + 65536, hsb + 65536,  1);
  rnn_step_k<<<256, 256, 0, stream>>>(sent + 131072, h1 + 65536,Wx1, Wh1, h1,         nullptr,      1);
  rnn_step_k<<<256, 256, 0, stream>>>(h1,            h2 + 65536,Wx2, Wh2, h2,         hsb + 131072, 1);

  // contexts: per-m GEMM against U[m]^T
  transpose_cvt<<<dim3(32, 32, 32), 256, 0, stream>>>(U, BIG, 1024, 1024);
  gemm_bf16<0><<<dim3(2, 8, 32), 256, 0, stream>>>(hsb, BIG, nullptr, nullptr, (void*)ctx, 192);

  // cur: GEMM against Wc^T with Ww gather + tanh epilogue
  transpose_cvt<<<dim3(32, 32, 1), 256, 0, stream>>>(Wc, WcT, 1024, 1024);
  gemm_bf16<1><<<dim3(47, 8, 1), 256, 0, stream>>>(ctx, WcT, Ww, x, (void*)cur, 5952);

  // y_sec: big GEMM against Wfc^T (reuses BIG), writes d_out directly
  transpose_cvt<<<dim3(1000, 32, 1), 256, 0, stream>>>(Wfc, BIG, 1024, 32000);
  gemm_bf16<2><<<12288, 256, 0, stream>>>(cur, BIG, nullptr, nullptr, (void*)out, 5952);
}

// Round 2
// 1454.034 us; speedup vs baseline: 1.0041x; 1.0041x over previous
//
#include <hip/hip_runtime.h>
#include <math.h>

typedef __bf16 bf16x8 __attribute__((ext_vector_type(8)));
typedef float f32x4 __attribute__((ext_vector_type(4)));
typedef unsigned short u16;

#define DI __device__ __forceinline__

DI u16 f2bf(float f) {
  union { float f; unsigned u; } v; v.f = f;
  unsigned r = v.u + 0x7FFFu + ((v.u >> 16) & 1u);  // RNE
  return (u16)(r >> 16);
}

DI void gload_lds16(const u16* g, u16* l) {
  // dest = wave-uniform base + lane*16B (HW semantics); src is per-lane.
  __builtin_amdgcn_global_load_lds(
      (const __attribute__((address_space(1))) unsigned int*)g,
      (__attribute__((address_space(3))) unsigned int*)l, 16, 0, 0);
}

// ---------------- one-hot rows (l=0 of each section) --------------------
__global__ __launch_bounds__(256) void onehot_k(const int* __restrict__ x,
                                                float* __restrict__ out) {
  int bs = blockIdx.x;            // s*64 + b
  int s = bs >> 6, b = bs & 63;
  long base = ((long)b * 96 + s * 32) * 32000;
  float4* o4 = (float4*)(out + base);
  float4 z; z.x = z.y = z.z = z.w = 0.f;
  for (int i = threadIdx.x; i < 8000; i += 256) o4[i] = z;
  __syncthreads();
  if (threadIdx.x == 0) {
    int tok = x[b * 128 + (s + 1) * 32];
    out[base + tok] = 1.0f;
  }
}

// ---------------- CSM: mean-pool + W_csm + tanh -> sent[s][b][h] --------
__global__ __launch_bounds__(256) void sent_k(const int* __restrict__ x,
    const float* __restrict__ emb, const float* __restrict__ Wcsm,
    float* __restrict__ sent) {
  int bs = blockIdx.x; int s = bs >> 6, b = bs & 63;
  __shared__ float mean[512];
  int t = threadIdx.x;
  float a0 = 0.f, a1 = 0.f;
  for (int lt = 0; lt < 32; ++lt) {
    int tok = x[b * 128 + s * 32 + lt];
    const float* e = emb + (long)tok * 512;
    a0 += e[t]; a1 += e[t + 256];
  }
  mean[t] = a0 * (1.f / 32.f); mean[t + 256] = a1 * (1.f / 32.f);
  __syncthreads();
  float acc[4] = {0.f, 0.f, 0.f, 0.f};
  for (int e = 0; e < 512; ++e) {
    float mv = mean[e];
    const float* wr_ = Wcsm + (long)e * 1024 + t;
#pragma unroll
    for (int j = 0; j < 4; ++j) acc[j] += mv * wr_[j * 256];
  }
#pragma unroll
  for (int j = 0; j < 4; ++j)
    sent[(long)bs * 1024 + t + j * 256] = tanhf(acc[j]);
}

// ---------------- RNN step: hout = tanh(x@Wx + h@Wh) --------------------
__global__ __launch_bounds__(256) void rnn_step_k(
    const float* __restrict__ xin, const float* __restrict__ hin,
    const float* __restrict__ Wx, const float* __restrict__ Wh,
    float* __restrict__ hout, u16* __restrict__ hsb, int useH) {
  int b = blockIdx.x >> 2, chunk = blockIdx.x & 3;
  int t = threadIdx.x;
  int h = chunk * 256 + t;
  __shared__ float xs[1024], hs_[1024];
#pragma unroll
  for (int i = 0; i < 4; ++i) {
    xs[t + 256 * i] = xin[b * 1024 + t + 256 * i];
    hs_[t + 256 * i] = useH ? hin[b * 1024 + t + 256 * i] : 0.f;
  }
  __syncthreads();
  float a0 = 0.f, a1 = 0.f, a2 = 0.f, a3 = 0.f;
  for (int k = 0; k < 1024; k += 4) {
    a0 += xs[k    ] * Wx[(long)(k    ) * 1024 + h] + hs_[k    ] * Wh[(long)(k    ) * 1024 + h];
    a1 += xs[k + 1] * Wx[(long)(k + 1) * 1024 + h] + hs_[k + 1] * Wh[(long)(k + 1) * 1024 + h];
    a2 += xs[k + 2] * Wx[(long)(k + 2) * 1024 + h] + hs_[k + 2] * Wh[(long)(k + 2) * 1024 + h];
    a3 += xs[k + 3] * Wx[(long)(k + 3) * 1024 + h] + hs_[k + 3] * Wh[(long)(k + 3) * 1024 + h];
  }
  float v = tanhf(a0 + a1 + a2 + a3);
  hout[b * 1024 + h] = v;
  if (hsb) hsb[b * 1024 + h] = f2bf(v);
}

// ---------------- transpose + fp32->bf16 : out[c][r] = bf16(in[r][c]) ---
__global__ __launch_bounds__(256) void transpose_cvt(
    const float* __restrict__ in, u16* __restrict__ out, int R, int C) {
  long zoff = (long)blockIdx.z * R * C;
  in += zoff; out += zoff;
  __shared__ float tile[32][33];
  int c0 = blockIdx.x * 32, r0 = blockIdx.y * 32;
  int tx = threadIdx.x & 31, ty = threadIdx.x >> 5;
#pragma unroll
  for (int i = 0; i < 4; ++i)
    tile[ty + 8 * i][tx] = in[(long)(r0 + ty + 8 * i) * C + c0 + tx];
  __syncthreads();
#pragma unroll
  for (int i = 0; i < 4; ++i)
    out[(long)(c0 + ty + 8 * i) * R + r0 + tx] = f2bf(tile[tx][ty + 8 * i]);
}

// ---------------- bf16 MFMA GEMM, 128x128 tile, BK=32, K=1024 -----------
// A: bf16 [M][1024] (MODE1: rows remapped r -> (r/31)*32 + r%31 + 1)
// Bt: bf16 [N][1024] (pre-transposed so K is contiguous)
// MODE 0: ctx  = tanh(hs @ U[mz])        -> bf16 ctx[(r*32+mz)*1024+col]
// MODE 1: cur  = tanh(acc + Ww[idx][col])-> bf16 cur[r*1024+col]
// MODE 2: ysec = acc                     -> f32 d_out scattered rows
template <int MODE>
__global__ __launch_bounds__(256) void gemm_bf16(
    const u16* __restrict__ A, const u16* __restrict__ Bt,
    const float* __restrict__ Ww, const int* __restrict__ xtok,
    void* __restrict__ outp, int M) {
  int mt, nt, mz = 0;
  if constexpr (MODE == 2) {
    // XCD-bijective chunking (12288 = 8*1536) + 8x8 tile groups for L2 reuse
    int flat = blockIdx.x;
    int wg = (flat & 7) * 1536 + (flat >> 3);
    int g = wg >> 6, w64 = wg & 63;
    mt = (g % 6) * 8 + (w64 & 7);
    nt = (g / 6) * 8 + (w64 >> 3);
    if (mt >= 47 || nt >= 250) return;
  } else {
    mt = blockIdx.x; nt = blockIdx.y; mz = blockIdx.z;
  }
  if constexpr (MODE == 0) Bt += (long)mz << 20;  // U slice [1024][1024]

  __shared__ __align__(16) u16 As[128 * 32];
  __shared__ __align__(16) u16 Bs[128 * 32];

  const int t = threadIdx.x;
  const int w = t >> 6, l = t & 63;
  const int lr = l & 15, lg = l >> 4;
  const int wr = w >> 1, wc = w & 1;

  int ar0 = mt * 128 + (t >> 2);
  int ar1 = ar0 + 64;
  if (ar0 >= M) ar0 = 0;
  if (ar1 >= M) ar1 = 0;
  long arow0, arow1;
  if constexpr (MODE == 1) {
    arow0 = (long)(ar0 / 31) * 32 + (ar0 % 31) + 1;
    arow1 = (long)(ar1 / 31) * 32 + (ar1 % 31) + 1;
  } else {
    arow0 = ar0; arow1 = ar1;
  }

  const u16* ga0 = A + arow0 * 1024 + (t & 3) * 8;
  const u16* ga1 = A + arow1 * 1024 + (t & 3) * 8;
  const u16* gb0 = Bt + ((long)nt * 128 + (t >> 2)) * 1024 + (t & 3) * 8;
  const u16* gb1 = gb0 + 64 * 1024;

  u16* dA0 = As + w * 512; u16* dA1 = As + 2048 + w * 512;
  u16* dB0 = Bs + w * 512; u16* dB1 = Bs + 2048 + w * 512;

  f32x4 acc[4][4] = {};

  for (int kt = 0; kt < 32; ++kt) {
    __syncthreads();
    gload_lds16(ga0, dA0); gload_lds16(ga1, dA1);
    gload_lds16(gb0, dB0); gload_lds16(gb1, dB1);
    ga0 += 32; ga1 += 32; gb0 += 32; gb1 += 32;
    __syncthreads();
    bf16x8 a[4], b[4];
#pragma unroll
    for (int m = 0; m < 4; ++m)
      a[m] = *(const bf16x8*)&As[(wr * 64 + m * 16 + lr) * 32 + lg * 8];
#pragma unroll
    for (int n = 0; n < 4; ++n)
      b[n] = *(const bf16x8*)&Bs[(wc * 64 + n * 16 + lr) * 32 + lg * 8];
#pragma unroll
    for (int m = 0; m < 4; ++m)
#pragma unroll
      for (int n = 0; n < 4; ++n)
        acc[m][n] = __builtin_amdgcn_mfma_f32_16x16x32_bf16(a[m], b[n], acc[m][n], 0, 0, 0);
  }

#pragma unroll
  for (int m = 0; m < 4; ++m) {
#pragma unroll
    for (int j = 0; j < 4; ++j) {
      int r = mt * 128 + wr * 64 + m * 16 + lg * 4 + j;
      if (r >= M) continue;
      if constexpr (MODE == 0) {
        u16* oc = (u16*)outp;
#pragma unroll
        for (int n = 0; n < 4; ++n) {
          int col = nt * 128 + wc * 64 + n * 16 + lr;
          oc[((long)r * 32 + mz) * 1024 + col] = f2bf(tanhf(acc[m][n][j]));
        }
      } else if constexpr (MODE == 1) {
        int sb = r / 31, l1 = r % 31;
        int s = sb >> 6, b = sb & 63;
        int widx = xtok[b * 128 + (s + 1) * 32 + l1];
        const float* wwr = Ww + (long)widx * 1024;
        u16* oc = (u16*)outp;
#pragma unroll
        for (int n = 0; n < 4; ++n) {
          int col = nt * 128 + wc * 64 + n * 16 + lr;
          oc[(long)r * 1024 + col] = f2bf(tanhf(acc[m][n][j] + wwr[col]));
        }
      } else {
        int s = r / 1984, rem = r % 1984;
        int b = rem / 31, l1 = rem % 31;
        float* o = (float*)outp + ((long)b * 96 + s * 32 + l1 + 1) * 32000;
#pragma unroll
        for (int n = 0; n < 4; ++n) {
          int col = nt * 128 + wc * 64 + n * 16 + lr;
          o[col] = acc[m][n][j];
        }
      }
    }
  }
}

// ------------------------------- launch ---------------------------------
extern "C" void kernel_launch(void* const* d_in, const int* in_sizes, int n_in,
                              void* d_out, int out_size, void* d_ws, size_t ws_size,
                              hipStream_t stream) {
  const int*   x    = (const int*)d_in[0];
  const float* emb  = (const float*)d_in[2];
  const float* Wcsm = (const float*)d_in[3];
  const float* Wx1  = (const float*)d_in[4];
  const float* Wh1  = (const float*)d_in[5];
  const float* Wx2  = (const float*)d_in[6];
  const float* Wh2  = (const float*)d_in[7];
  const float* U    = (const float*)d_in[8];
  const float* Ww   = (const float*)d_in[9];
  const float* Wc   = (const float*)d_in[10];
  const float* Wfc  = (const float*)d_in[11];
  float* out = (float*)d_out;

  // workspace carve (~96.2 MB): BIG is shared between U^T (stage C) and
  // Wfc^T (stage E) — lifetimes are stream-ordered disjoint.
  char* ws = (char*)d_ws;
  float* sent = (float*)(ws + 0);          //  786432 B  [3][64][1024] f32
  float* h1   = (float*)(ws + 786432);     //  524288 B  2x [64][1024]
  float* h2   = (float*)(ws + 1310720);    //  524288 B
  u16*   hsb  = (u16*)(ws + 1835008);      //  393216 B  [3][64][1024] bf16
  u16*   ctx  = (u16*)(ws + 2228224);      // 12582912 B [192][32][1024] bf16
  u16*   cur  = (u16*)(ws + 14811136);     // 12189696 B [5952][1024] bf16
  u16*   WcT  = (u16*)(ws + 27000832);     //  2097152 B [1024][1024] bf16
  u16*   BIG  = (u16*)(ws + 29097984);     // 67108864 B U^T then Wfc^T

  onehot_k<<<192, 256, 0, stream>>>(x, out);
  sent_k<<<192, 256, 0, stream>>>(x, emb, Wcsm, sent);

  // RNN: 3 sentences x (h1, h2); ping-pong buffers; hs[s] = h2 after step s
  rnn_step_k<<<256, 256, 0, stream>>>(sent,          h1,        Wx1, Wh1, h1,         nullptr,      0);
  rnn_step_k<<<256, 256, 0, stream>>>(h1,            h2,        Wx2, Wh2, h2,         hsb,          0);
  rnn_step_k<<<256, 256, 0, stream>>>(sent + 65536,  h1,        Wx1, Wh1, h1 + 65536, nullptr,      1);
  rnn_step_k<<<256, 256, 0, stream>>>(h1 + 65536,    h2,        Wx2, Wh2, h2 + 65536, hsb + 65536,  1);
  rnn_step_k<<<256, 256, 0, stream>>>(sent + 131072, h1 + 65536,Wx1, Wh1, h1,         nullptr,      1);
  rnn_step_k<<<256, 256, 0, stream>>>(h1,            h2 + 65536,Wx2, Wh2, h2,         hsb + 131072, 1);

  // contexts: per-m GEMM against U[m]^T
  transpose_cvt<<<dim3(32, 32, 32), 256, 0, stream>>>(U, BIG, 1024, 1024);
  gemm_bf16<0><<<dim3(2, 8, 32), 256, 0, stream>>>(hsb, BIG, nullptr, nullptr, (void*)ctx, 192);

  // cur: GEMM against Wc^T with Ww gather + tanh epilogue
  transpose_cvt<<<dim3(32, 32, 1), 256, 0, stream>>>(Wc, WcT, 1024, 1024);
  gemm_bf16<1><<<dim3(47, 8, 1), 256, 0, stream>>>(ctx, WcT, Ww, x, (void*)cur, 5952);

  // y_sec: big GEMM against Wfc^T (reuses BIG), writes d_out directly
  transpose_cvt<<<dim3(1000, 32, 1), 256, 0, stream>>>(Wfc, BIG, 1024, 32000);
  gemm_bf16<2><<<12288, 256, 0, stream>>>(cur, BIG, nullptr, nullptr, (void*)out, 5952);
}

// Round 3
// 999.470 us; speedup vs baseline: 1.4608x; 1.4548x over previous
//
#include <hip/hip_runtime.h>
#include <math.h>

typedef __bf16 bf16x8 __attribute__((ext_vector_type(8)));
typedef float f32x4 __attribute__((ext_vector_type(4)));
typedef unsigned short u16;

#define DI __device__ __forceinline__

DI u16 f2bf(float f) {
  union { float f; unsigned u; } v; v.f = f;
  unsigned r = v.u + 0x7FFFu + ((v.u >> 16) & 1u);  // RNE
  return (u16)(r >> 16);
}

DI void gload_lds16(const u16* g, u16* l) {
  // dest = wave-uniform base + lane*16B (HW semantics); src is per-lane.
  __builtin_amdgcn_global_load_lds(
      (const __attribute__((address_space(1))) unsigned int*)g,
      (__attribute__((address_space(3))) unsigned int*)l, 16, 0, 0);
}

// ---------------- one-hot rows (l=0 of each section) --------------------
__global__ __launch_bounds__(256) void onehot_k(const int* __restrict__ x,
                                                float* __restrict__ out) {
  int bid = blockIdx.x;            // 1536 = 192 bs * 8 chunks
  int bs = bid >> 3, chunk = bid & 7;
  int s = bs >> 6, b = bs & 63;
  long base = ((long)b * 96 + s * 32) * 32000;
  float4* o4 = (float4*)(out + base) + chunk * 1000;
  float4 z; z.x = z.y = z.z = z.w = 0.f;
  for (int i = threadIdx.x; i < 1000; i += 256) o4[i] = z;
  __syncthreads();
  if (threadIdx.x == 0) {
    int tok = x[b * 128 + (s + 1) * 32];
    if (tok / 4000 == chunk) out[base + tok] = 1.0f;
  }
}

// ---------------- mean-pool embeddings -> sentM [192][512] bf16 ---------
__global__ __launch_bounds__(256) void meanpool_k(const int* __restrict__ x,
    const float* __restrict__ emb, u16* __restrict__ sentM) {
  int bs = blockIdx.x; int s = bs >> 6, b = bs & 63;
  int t = threadIdx.x;
  float a0 = 0.f, a1 = 0.f;
  for (int lt = 0; lt < 32; ++lt) {
    int tok = x[b * 128 + s * 32 + lt];
    const float* e = emb + (long)tok * 512;
    a0 += e[t]; a1 += e[t + 256];
  }
  sentM[(long)bs * 512 + t] = f2bf(a0 * (1.f / 32.f));
  sentM[(long)bs * 512 + t + 256] = f2bf(a1 * (1.f / 32.f));
}

// ---------------- transpose + fp32->bf16 : out[c][r] = bf16(in[r][c]) ---
__global__ __launch_bounds__(256) void transpose_cvt(
    const float* __restrict__ in, u16* __restrict__ out, int R, int C,
    int ostride) {
  in += (long)blockIdx.z * R * C;
  out += (long)blockIdx.z * (long)C * ostride;
  __shared__ float tile[32][33];
  int c0 = blockIdx.x * 32, r0 = blockIdx.y * 32;
  int tx = threadIdx.x & 31, ty = threadIdx.x >> 5;
#pragma unroll
  for (int i = 0; i < 4; ++i)
    tile[ty + 8 * i][tx] = in[(long)(r0 + ty + 8 * i) * C + c0 + tx];
  __syncthreads();
#pragma unroll
  for (int i = 0; i < 4; ++i)
    out[(long)(c0 + ty + 8 * i) * ostride + r0 + tx] = f2bf(tile[tx][ty + 8 * i]);
}

// ---------------- small MFMA GEMM: out = tanh(A0|A1 @ B^T), N=1024 ------
// A-rows: k<kSplit from A0 (stride Astride), else A1 (stride 1024).
// Bt: bf16 [1024][Bstride], K contiguous. LDS K-major 16B units.
__global__ __launch_bounds__(256) void gemm_small(
    const u16* __restrict__ A0, const u16* __restrict__ A1,
    const u16* __restrict__ Bt, u16* __restrict__ outp,
    int M, int K, int kSplit, int Astride, int Bstride) {
  int mt = blockIdx.x, ntb = blockIdx.y;
  __shared__ __align__(16) u16 As[2048];   // [kg0..3][row0..63] x 8 u16
  __shared__ __align__(16) u16 Bs[4096];   // [kg0..3][col0..127] x 8 u16
  const int t = threadIdx.x;
  const int w = t >> 6, l = t & 63, lr = l & 15, lg = l >> 4;
  int ar = mt * 64 + (t & 63); if (ar >= M) ar = M - 1;
  const u16* pB = Bt + (long)(ntb * 128 + (t & 127)) * Bstride + (t >> 7) * 8;
  f32x4 acc[4][2] = {};
  for (int k0 = 0; k0 < K; k0 += 32) {
    __syncthreads();
    const u16* srcA = (k0 < kSplit)
        ? A0 + (long)ar * Astride + k0 + w * 8
        : A1 + (long)ar * 1024 + (k0 - kSplit) + w * 8;
    gload_lds16(srcA, As + w * 512);
    gload_lds16(pB + k0, Bs + w * 512);
    gload_lds16(pB + k0 + 16, Bs + 2048 + w * 512);
    __syncthreads();
    bf16x8 a[4], b[2];
#pragma unroll
    for (int mf = 0; mf < 4; ++mf)
      a[mf] = *(const bf16x8*)(As + (lg * 64 + mf * 16 + lr) * 8);
#pragma unroll
    for (int nf = 0; nf < 2; ++nf)
      b[nf] = *(const bf16x8*)(Bs + (lg * 128 + w * 32 + nf * 16 + lr) * 8);
#pragma unroll
    for (int mf = 0; mf < 4; ++mf)
#pragma unroll
      for (int nf = 0; nf < 2; ++nf)
        acc[mf][nf] = __builtin_amdgcn_mfma_f32_16x16x32_bf16(a[mf], b[nf], acc[mf][nf], 0, 0, 0);
  }
#pragma unroll
  for (int mf = 0; mf < 4; ++mf)
#pragma unroll
    for (int j = 0; j < 4; ++j) {
      int r = mt * 64 + mf * 16 + lg * 4 + j;
      if (r < M) {
        u16* o = outp + (long)r * 1024 + ntb * 128 + w * 32;
#pragma unroll
        for (int nf = 0; nf < 2; ++nf)
          o[nf * 16 + lr] = f2bf(tanhf(acc[mf][nf][j]));
      }
    }
}

// ---------------- mid GEMM (128x128, BK=32) for ctx / cur ----------------
template <int MODE>
__global__ __launch_bounds__(256) void gemm_bf16(
    const u16* __restrict__ A, const u16* __restrict__ Bt,
    const float* __restrict__ Ww, const int* __restrict__ xtok,
    void* __restrict__ outp, int M) {
  int mt = blockIdx.x, nt = blockIdx.y, mz = blockIdx.z;
  if constexpr (MODE == 0) Bt += (long)mz << 20;  // U slice [1024][1024]

  __shared__ __align__(16) u16 As[128 * 32];
  __shared__ __align__(16) u16 Bs[128 * 32];

  const int t = threadIdx.x;
  const int w = t >> 6, l = t & 63;
  const int lr = l & 15, lg = l >> 4;
  const int wr = w >> 1, wc = w & 1;

  int ar0 = mt * 128 + (t >> 2);
  int ar1 = ar0 + 64;
  if (ar0 >= M) ar0 = 0;
  if (ar1 >= M) ar1 = 0;
  long arow0, arow1;
  if constexpr (MODE == 1) {
    arow0 = (long)(ar0 / 31) * 32 + (ar0 % 31) + 1;
    arow1 = (long)(ar1 / 31) * 32 + (ar1 % 31) + 1;
  } else {
    arow0 = ar0; arow1 = ar1;
  }

  const u16* ga0 = A + arow0 * 1024 + (t & 3) * 8;
  const u16* ga1 = A + arow1 * 1024 + (t & 3) * 8;
  const u16* gb0 = Bt + ((long)nt * 128 + (t >> 2)) * 1024 + (t & 3) * 8;
  const u16* gb1 = gb0 + 64 * 1024;

  u16* dA0 = As + w * 512; u16* dA1 = As + 2048 + w * 512;
  u16* dB0 = Bs + w * 512; u16* dB1 = Bs + 2048 + w * 512;

  f32x4 acc[4][4] = {};

  for (int kt = 0; kt < 32; ++kt) {
    __syncthreads();
    gload_lds16(ga0, dA0); gload_lds16(ga1, dA1);
    gload_lds16(gb0, dB0); gload_lds16(gb1, dB1);
    ga0 += 32; ga1 += 32; gb0 += 32; gb1 += 32;
    __syncthreads();
    bf16x8 a[4], b[4];
#pragma unroll
    for (int m = 0; m < 4; ++m)
      a[m] = *(const bf16x8*)&As[(wr * 64 + m * 16 + lr) * 32 + lg * 8];
#pragma unroll
    for (int n = 0; n < 4; ++n)
      b[n] = *(const bf16x8*)&Bs[(wc * 64 + n * 16 + lr) * 32 + lg * 8];
#pragma unroll
    for (int m = 0; m < 4; ++m)
#pragma unroll
      for (int n = 0; n < 4; ++n)
        acc[m][n] = __builtin_amdgcn_mfma_f32_16x16x32_bf16(a[m], b[n], acc[m][n], 0, 0, 0);
  }

#pragma unroll
  for (int m = 0; m < 4; ++m) {
#pragma unroll
    for (int j = 0; j < 4; ++j) {
      int r = mt * 128 + wr * 64 + m * 16 + lg * 4 + j;
      if (r >= M) continue;
      if constexpr (MODE == 0) {
        u16* oc = (u16*)outp;
#pragma unroll
        for (int n = 0; n < 4; ++n) {
          int col = nt * 128 + wc * 64 + n * 16 + lr;
          oc[((long)r * 32 + mz) * 1024 + col] = f2bf(tanhf(acc[m][n][j]));
        }
      } else {
        int sb = r / 31, l1 = r % 31;
        int s = sb >> 6, b = sb & 63;
        int widx = xtok[b * 128 + (s + 1) * 32 + l1];
        const float* wwr = Ww + (long)widx * 1024;
        u16* oc = (u16*)outp;
#pragma unroll
        for (int n = 0; n < 4; ++n) {
          int col = nt * 128 + wc * 64 + n * 16 + lr;
          oc[(long)r * 1024 + col] = f2bf(tanhf(acc[m][n][j] + wwr[col]));
        }
      }
    }
  }
}

// ---------------- BIG GEMM: 256x256 tile, BK=64, 8-phase schedule --------
// C[5952][32000] f32 (scattered rows of d_out) = A[5952][1024] @ Bt^T.
// LDS per half-tile: K-major 16B units [kgroup0..7][row0..127] (conflict-free
// quarter-wave ds_read_b128; global_load_lds stays linear in lane order).
#define NOSTAGE ((void)0)
#define VM4 asm volatile("s_waitcnt vmcnt(4)" ::: "memory")
#define VM0 asm volatile("s_waitcnt vmcnt(0)" ::: "memory")

#define STAGE_A(H, KT) do {                                                \
    const u16* _s = ((H) ? pA1 : pA0) + (KT) * 64;                         \
    u16* _d = lds + ((KT) & 1) * 16384 + (H) * 8192 + w * 512;             \
    gload_lds16(_s, _d); gload_lds16(_s + 32, _d + 4096);                  \
  } while (0)
#define STAGE_B(H, KT) do {                                                \
    const u16* _s = ((H) ? pB1 : pB0) + (KT) * 64;                         \
    u16* _d = lds + 32768 + ((KT) & 1) * 16384 + (H) * 8192 + w * 512;     \
    gload_lds16(_s, _d); gload_lds16(_s + 32, _d + 4096);                  \
  } while (0)

#define PHASE(ABASE, MH, NH, RA, RB, STAGESTMT, WAITSTMT) do {             \
    if (RA) {                                                              \
      _Pragma("unroll") for (int ks = 0; ks < 2; ++ks)                     \
      _Pragma("unroll") for (int mf = 0; mf < 4; ++mf)                     \
        a[mf][ks] = *(const bf16x8*)(lds + (ABASE) + (MH) * 8192 + laneA + \
                                     ks * 4096 + mf * 128);                \
    }                                                                      \
    if (RB) {                                                              \
      _Pragma("unroll") for (int ks = 0; ks < 2; ++ks)                     \
      _Pragma("unroll") for (int nf = 0; nf < 2; ++nf)                     \
        b[NH][nf][ks] = *(const bf16x8*)(lds + 32768 + (ABASE) +           \
                                         (NH) * 8192 + laneB +             \
                                         ks * 4096 + nf * 128);            \
    }                                                                      \
    STAGESTMT;                                                             \
    __builtin_amdgcn_s_barrier();                                          \
    asm volatile("s_waitcnt lgkmcnt(0)" ::: "memory");                     \
    __builtin_amdgcn_sched_barrier(0);                                     \
    __builtin_amdgcn_s_setprio(1);                                         \
    _Pragma("unroll") for (int ks = 0; ks < 2; ++ks)                       \
    _Pragma("unroll") for (int mf = 0; mf < 4; ++mf)                       \
    _Pragma("unroll") for (int nf = 0; nf < 2; ++nf)                       \
      acc[(MH) * 4 + mf][(NH) * 2 + nf] =                                  \
          __builtin_amdgcn_mfma_f32_16x16x32_bf16(                         \
              a[mf][ks], b[NH][nf][ks],                                    \
              acc[(MH) * 4 + mf][(NH) * 2 + nf], 0, 0, 0);                 \
    __builtin_amdgcn_s_setprio(0);                                         \
    WAITSTMT;                                                              \
    __builtin_amdgcn_s_barrier();                                          \
  } while (0)

__global__ __launch_bounds__(512, 2) void gemm_big(
    const u16* __restrict__ A, const u16* __restrict__ Bt,
    float* __restrict__ out) {
  int bid = blockIdx.x;                       // 3000 = 8 * 375 (bijective)
  int wg = (bid & 7) * 375 + (bid >> 3);
  int mt = wg % 24, nt = wg / 24;             // 24 x 125 tiles

  __shared__ __align__(16) u16 lds[65536];    // A [0,32768) | B [32768,65536)

  const int t = threadIdx.x;
  const int w = t >> 6, l = t & 63;
  const int lr = l & 15, lg = l >> 4;
  const int wm = w >> 2, wn = w & 3;          // 2 x 4 waves
  const int laneA = (lg * 128 + wm * 64 + lr) * 8;
  const int laneB = (lg * 128 + wn * 32 + lr) * 8;

  int arow0 = mt * 256 + (t & 127);
  int arow1 = arow0 + 128;
  if (arow0 > 5951) arow0 = 5951;
  if (arow1 > 5951) arow1 = 5951;
  const u16* pA0 = A + (long)arow0 * 1024 + (t >> 7) * 8;
  const u16* pA1 = A + (long)arow1 * 1024 + (t >> 7) * 8;
  const u16* pB0 = Bt + ((long)nt * 256 + (t & 127)) * 1024 + (t >> 7) * 8;
  const u16* pB1 = pB0 + 128 * 1024;

  f32x4 acc[8][4] = {};
  bf16x8 a[4][2], b[2][2][2];

  // prologue: Ah0(0) Bh0(0) Bh1(0) Ah1(0) Ah0(1) Bh0(1); wait tile0; barrier
  STAGE_A(0, 0); STAGE_B(0, 0); STAGE_B(1, 0); STAGE_A(1, 0);
  STAGE_A(0, 1); STAGE_B(0, 1);
  VM4;
  __builtin_amdgcn_s_barrier();

  for (int g = 0; g < 14; g += 2) {
    PHASE(0,     0, 0, 1, 1, STAGE_B(1, g + 1), NOSTAGE);
    PHASE(0,     0, 1, 0, 1, STAGE_A(1, g + 1), NOSTAGE);
    PHASE(0,     1, 0, 1, 0, STAGE_A(0, g + 2), NOSTAGE);
    PHASE(0,     1, 1, 0, 0, STAGE_B(0, g + 2), VM4);
    PHASE(16384, 0, 0, 1, 1, STAGE_B(1, g + 2), NOSTAGE);
    PHASE(16384, 0, 1, 0, 1, STAGE_A(1, g + 2), NOSTAGE);
    PHASE(16384, 1, 0, 1, 0, STAGE_A(0, g + 3), NOSTAGE);
    PHASE(16384, 1, 1, 0, 0, STAGE_B(0, g + 3), VM4);
  }
  // group 14 (buf 0): stage tile 15's trailing halves; tile 16 doesn't exist
  PHASE(0,     0, 0, 1, 1, STAGE_B(1, 15), NOSTAGE);
  PHASE(0,     0, 1, 0, 1, STAGE_A(1, 15), NOSTAGE);
  PHASE(0,     1, 0, 1, 0, NOSTAGE, NOSTAGE);
  PHASE(0,     1, 1, 0, 0, NOSTAGE, VM0);
  // group 15 (buf 1): pure drain
  PHASE(16384, 0, 0, 1, 1, NOSTAGE, NOSTAGE);
  PHASE(16384, 0, 1, 0, 1, NOSTAGE, NOSTAGE);
  PHASE(16384, 1, 0, 1, 0, NOSTAGE, NOSTAGE);
  PHASE(16384, 1, 1, 0, 0, NOSTAGE, NOSTAGE);

  // epilogue: scatter f32 rows of d_out
#pragma unroll
  for (int mh = 0; mh < 2; ++mh)
#pragma unroll
    for (int mf = 0; mf < 4; ++mf)
#pragma unroll
      for (int j = 0; j < 4; ++j) {
        int r = mt * 256 + mh * 128 + wm * 64 + mf * 16 + lg * 4 + j;
        if (r < 5952) {
          int s = r / 1984, rem = r % 1984;
          int bb = rem / 31, l1 = rem % 31;
          float* o = out + ((long)bb * 96 + s * 32 + l1 + 1) * 32000 +
                     nt * 256 + wn * 32;
#pragma unroll
          for (int nh = 0; nh < 2; ++nh)
#pragma unroll
            for (int nf = 0; nf < 2; ++nf)
              o[nh * 128 + nf * 16 + lr] = acc[mh * 4 + mf][nh * 2 + nf][j];
        }
      }
}

// ------------------------------- launch ---------------------------------
extern "C" void kernel_launch(void* const* d_in, const int* in_sizes, int n_in,
                              void* d_out, int out_size, void* d_ws, size_t ws_size,
                              hipStream_t stream) {
  const int*   x    = (const int*)d_in[0];
  const float* emb  = (const float*)d_in[2];
  const float* Wcsm = (const float*)d_in[3];
  const float* Wx1  = (const float*)d_in[4];
  const float* Wh1  = (const float*)d_in[5];
  const float* Wx2  = (const float*)d_in[6];
  const float* Wh2  = (const float*)d_in[7];
  const float* U    = (const float*)d_in[8];
  const float* Ww   = (const float*)d_in[9];
  const float* Wc   = (const float*)d_in[10];
  const float* Wfc  = (const float*)d_in[11];
  float* out = (float*)d_out;

  // workspace carve (~90.8 MB). Lifetime overlaps (stream-ordered):
  //   ctx region also hosts WcsmT/WxhT1/WxhT2 (dead before ctx is written);
  //   BIG hosts U^T then Wfc^T.
  char* ws = (char*)d_ws;
  u16* sentM = (u16*)(ws + 0);          //  196608 [192][512]
  u16* sentH = (u16*)(ws + 196608);     //  393216 [192][1024]
  u16* h1a   = (u16*)(ws + 589824);     //  131072 [64][1024]
  u16* h1b   = (u16*)(ws + 720896);     //  131072
  u16* hsb   = (u16*)(ws + 851968);     //  393216 [192][1024]
  u16* ctx   = (u16*)(ws + 1245184);    // 12582912 [192*32][1024]
  u16* WcsmT = (u16*)(ws + 1245184);    //  1048576 [1024][512]   (pre-ctx)
  u16* WxhT1 = (u16*)(ws + 2293760);    //  4194304 [1024][2048]  (pre-ctx)
  u16* WxhT2 = (u16*)(ws + 6488064);    //  4194304 [1024][2048]  (pre-ctx)
  u16* cur   = (u16*)(ws + 13828096);   // 12189696 [5952][1024]
  u16* WcT   = (u16*)(ws + 26017792);   //  2097152 [1024][1024]
  u16* BIG   = (u16*)(ws + 28114944);   // 67108864 U^T then Wfc^T

  onehot_k<<<1536, 256, 0, stream>>>(x, out);

  // weight prep (independent)
  transpose_cvt<<<dim3(32, 16, 1), 256, 0, stream>>>(Wcsm, WcsmT, 512, 1024, 512);
  transpose_cvt<<<dim3(32, 32, 1), 256, 0, stream>>>(Wx1, WxhT1, 1024, 1024, 2048);
  transpose_cvt<<<dim3(32, 32, 1), 256, 0, stream>>>(Wh1, WxhT1 + 1024, 1024, 1024, 2048);
  transpose_cvt<<<dim3(32, 32, 1), 256, 0, stream>>>(Wx2, WxhT2, 1024, 1024, 2048);
  transpose_cvt<<<dim3(32, 32, 1), 256, 0, stream>>>(Wh2, WxhT2 + 1024, 1024, 1024, 2048);
  transpose_cvt<<<dim3(32, 32, 1), 256, 0, stream>>>(Wc, WcT, 1024, 1024, 1024);

  // CSM: mean-pool + tanh(sentM @ Wcsm)
  meanpool_k<<<192, 256, 0, stream>>>(x, emb, sentM);
  gemm_small<<<dim3(3, 8), 256, 0, stream>>>(sentM, sentM, WcsmT, sentH, 192, 512, 512, 512, 512);

  // RNN: h = tanh([x h] @ [Wx;Wh]) via concat-K; hs[s] lands in hsb rows s*64..
  gemm_small<<<dim3(1, 8), 256, 0, stream>>>(sentH,          h1a, WxhT1, h1a,           64, 1024, 1024, 1024, 2048);
  gemm_small<<<dim3(1, 8), 256, 0, stream>>>(h1a,            h1a, WxhT2, hsb,           64, 1024, 1024, 1024, 2048);
  gemm_small<<<dim3(1, 8), 256, 0, stream>>>(sentH + 65536,  h1a, WxhT1, h1b,           64, 2048, 1024, 1024, 2048);
  gemm_small<<<dim3(1, 8), 256, 0, stream>>>(h1b,            hsb, WxhT2, hsb + 65536,   64, 2048, 1024, 1024, 2048);
  gemm_small<<<dim3(1, 8), 256, 0, stream>>>(sentH + 131072, h1b, WxhT1, h1a,           64, 2048, 1024, 1024, 2048);
  gemm_small<<<dim3(1, 8), 256, 0, stream>>>(h1a, hsb + 65536, WxhT2, hsb + 131072,     64, 2048, 1024, 1024, 2048);

  // contexts: per-m GEMM against U[m]^T
  transpose_cvt<<<dim3(32, 32, 32), 256, 0, stream>>>(U, BIG, 1024, 1024, 1024);
  gemm_bf16<0><<<dim3(2, 8, 32), 256, 0, stream>>>(hsb, BIG, nullptr, nullptr, (void*)ctx, 192);

  // cur: GEMM against Wc^T with Ww gather + tanh epilogue
  gemm_bf16<1><<<dim3(47, 8, 1), 256, 0, stream>>>(ctx, WcT, Ww, x, (void*)cur, 5952);

  // y_sec: 8-phase 256^2 GEMM against Wfc^T (BIG reused), writes d_out
  transpose_cvt<<<dim3(1000, 32, 1), 256, 0, stream>>>(Wfc, BIG, 1024, 32000, 1024);
  gemm_big<<<3000, 512, 0, stream>>>(cur, BIG, out);
}

// Round 5
// 922.220 us; speedup vs baseline: 1.5832x; 1.0838x over previous
//
#include <hip/hip_runtime.h>
#include <math.h>

typedef __bf16 bf16x8 __attribute__((ext_vector_type(8)));
typedef float f32x4 __attribute__((ext_vector_type(4)));
typedef unsigned short u16;
typedef u16 u16x8 __attribute__((ext_vector_type(8)));

#define DI __device__ __forceinline__

DI u16 f2bf(float f) {
  union { float f; unsigned u; } v; v.f = f;
  unsigned r = v.u + 0x7FFFu + ((v.u >> 16) & 1u);  // RNE
  return (u16)(r >> 16);
}

DI void gload_lds16(const u16* g, u16* l) {
  // dest = wave-uniform base + lane*16B (HW semantics); src is per-lane.
  __builtin_amdgcn_global_load_lds(
      (const __attribute__((address_space(1))) unsigned int*)g,
      (__attribute__((address_space(3))) unsigned int*)l, 16, 0, 0);
}

// ---------------- one-hot rows (l=0 of each section) --------------------
__global__ __launch_bounds__(256) void onehot_k(const int* __restrict__ x,
                                                float* __restrict__ out) {
  int bid = blockIdx.x;            // 1536 = 192 bs * 8 chunks
  int bs = bid >> 3, chunk = bid & 7;
  int s = bs >> 6, b = bs & 63;
  long base = ((long)b * 96 + s * 32) * 32000;
  float4* o4 = (float4*)(out + base) + chunk * 1000;
  float4 z; z.x = z.y = z.z = z.w = 0.f;
  for (int i = threadIdx.x; i < 1000; i += 256) o4[i] = z;
  __syncthreads();
  if (threadIdx.x == 0) {
    int tok = x[b * 128 + (s + 1) * 32];
    if (tok / 4000 == chunk) out[base + tok] = 1.0f;
  }
}

// ---------------- mean-pool embeddings -> sentM [192][512] bf16 ---------
__global__ __launch_bounds__(256) void meanpool_k(const int* __restrict__ x,
    const float* __restrict__ emb, u16* __restrict__ sentM) {
  int bs = blockIdx.x; int s = bs >> 6, b = bs & 63;
  int t = threadIdx.x;
  float a0 = 0.f, a1 = 0.f;
  for (int lt = 0; lt < 32; ++lt) {
    int tok = x[b * 128 + s * 32 + lt];
    const float* e = emb + (long)tok * 512;
    a0 += e[t]; a1 += e[t + 256];
  }
  sentM[(long)bs * 512 + t] = f2bf(a0 * (1.f / 32.f));
  sentM[(long)bs * 512 + t + 256] = f2bf(a1 * (1.f / 32.f));
}

// ------- transpose + cvt, 64-wide output rows (full 128B bf16 lines) ----
// out[c*ostride + r] = bf16(in[r*C + c]); tile 64 r x 32 c; XOR-swizzled LDS.
DI void transpose64_body(const float* __restrict__ in, u16* __restrict__ out,
                         int C, int ostride) {
  __shared__ float tile[32 * 65];
  int c0 = blockIdx.x * 32, r0 = blockIdx.y * 64;
  int t = threadIdx.x;
  int cc = t & 31, rr0 = t >> 5;
#pragma unroll
  for (int i = 0; i < 8; ++i) {
    int rr = rr0 + 8 * i;
    tile[cc * 65 + (rr ^ ((cc & 7) << 3))] = in[(long)(r0 + rr) * C + c0 + cc];
  }
  __syncthreads();
  int cj = t >> 3, rj = t & 7;
  u16x8 v;
#pragma unroll
  for (int k = 0; k < 8; ++k)
    v[k] = f2bf(tile[cj * 65 + ((rj * 8 + k) ^ ((cj & 7) << 3))]);
  *(u16x8*)(out + (long)(c0 + cj) * ostride + r0 + rj * 8) = v;
}

__global__ __launch_bounds__(256) void transpose64(
    const float* __restrict__ in, u16* __restrict__ out, int R, int C,
    int ostride) {
  in += (long)blockIdx.z * (long)R * C;
  out += (long)blockIdx.z * (long)C * ostride;
  transpose64_body(in, out, C, ostride);
}

struct TJob { const float* in; u16* out; int R; int ostride; };
struct TJobs { TJob j[6]; };
__global__ __launch_bounds__(256) void transpose64_multi(TJobs jobs) {
  TJob jb = jobs.j[blockIdx.z];                 // all jobs C = 1024
  if ((int)(blockIdx.y * 64) >= jb.R) return;
  transpose64_body(jb.in, jb.out, 1024, jb.ostride);
}

// ---------------- small MFMA GEMM: out = tanh(A0|A1 @ B^T), N=1024 ------
// Depth-2 pipelined (3 LDS buffers, counted vmcnt), raw barriers.
__global__ __launch_bounds__(256) void gemm_small(
    const u16* __restrict__ A0, const u16* __restrict__ A1,
    const u16* __restrict__ Bt, u16* __restrict__ outp,
    int M, int K, int kSplit, int Astride, int Bstride) {
  int mt = blockIdx.x, ntb = blockIdx.y;
  __shared__ __align__(16) u16 As[3][2048];   // [kg0..3][row0..63] x 8 u16
  __shared__ __align__(16) u16 Bs[3][4096];   // [kg0..3][col0..127] x 8 u16
  const int t = threadIdx.x;
  const int w = t >> 6, l = t & 63, lr = l & 15, lg = l >> 4;
  int ar = mt * 64 + (t & 63); if (ar >= M) ar = M - 1;
  const u16* pB = Bt + (long)(ntb * 128 + (t & 127)) * Bstride + (t >> 7) * 8;
  const int ntk = K >> 5;

  auto STG = [&](int buf, int kt) {
    int k0 = kt << 5;
    const u16* srcA = (k0 < kSplit)
        ? A0 + (long)ar * Astride + k0 + w * 8
        : A1 + (long)ar * 1024 + (k0 - kSplit) + w * 8;
    gload_lds16(srcA, &As[buf][w * 512]);
    gload_lds16(pB + k0, &Bs[buf][w * 512]);
    gload_lds16(pB + k0 + 16, &Bs[buf][2048 + w * 512]);
  };
  STG(0, 0);
  if (ntk > 1) STG(1, 1);

  f32x4 acc[4][2] = {};
  for (int kt = 0; kt < ntk; ++kt) {
    int cb = kt % 3;
    if (kt + 2 < ntk) {
      STG((kt + 2) % 3, kt + 2);
      asm volatile("s_waitcnt vmcnt(6)" ::: "memory");
    } else if (kt + 1 < ntk) {
      asm volatile("s_waitcnt vmcnt(3)" ::: "memory");
    } else {
      asm volatile("s_waitcnt vmcnt(0)" ::: "memory");
    }
    __builtin_amdgcn_s_barrier();
    __builtin_amdgcn_sched_barrier(0);
    bf16x8 a[4], b[2];
#pragma unroll
    for (int mf = 0; mf < 4; ++mf)
      a[mf] = *(const bf16x8*)(&As[cb][(lg * 64 + mf * 16 + lr) * 8]);
#pragma unroll
    for (int nf = 0; nf < 2; ++nf)
      b[nf] = *(const bf16x8*)(&Bs[cb][(lg * 128 + w * 32 + nf * 16 + lr) * 8]);
#pragma unroll
    for (int mf = 0; mf < 4; ++mf)
#pragma unroll
      for (int nf = 0; nf < 2; ++nf)
        acc[mf][nf] = __builtin_amdgcn_mfma_f32_16x16x32_bf16(a[mf], b[nf], acc[mf][nf], 0, 0, 0);
    __builtin_amdgcn_s_barrier();
    __builtin_amdgcn_sched_barrier(0);
  }
#pragma unroll
  for (int mf = 0; mf < 4; ++mf)
#pragma unroll
    for (int j = 0; j < 4; ++j) {
      int r = mt * 64 + mf * 16 + lg * 4 + j;
      if (r < M) {
        u16* o = outp + (long)r * 1024 + ntb * 128 + w * 32;
#pragma unroll
        for (int nf = 0; nf < 2; ++nf)
          o[nf * 16 + lr] = f2bf(tanhf(acc[mf][nf][j]));
      }
    }
}

// ---------------- mid GEMM (128x128, BK=32) for ctx / cur ----------------
template <int MODE>
__global__ __launch_bounds__(256) void gemm_bf16(
    const u16* __restrict__ A, const u16* __restrict__ Bt,
    const float* __restrict__ Ww, const int* __restrict__ xtok,
    void* __restrict__ outp, int M) {
  int mt = blockIdx.x, nt = blockIdx.y, mz = blockIdx.z;
  if constexpr (MODE == 0) Bt += (long)mz << 20;  // U slice [1024][1024]

  __shared__ __align__(16) u16 As[128 * 32];
  __shared__ __align__(16) u16 Bs[128 * 32];

  const int t = threadIdx.x;
  const int w = t >> 6, l = t & 63;
  const int lr = l & 15, lg = l >> 4;
  const int wr = w >> 1, wc = w & 1;

  int ar0 = mt * 128 + (t >> 2);
  int ar1 = ar0 + 64;
  if (ar0 >= M) ar0 = 0;
  if (ar1 >= M) ar1 = 0;
  long arow0, arow1;
  if constexpr (MODE == 1) {
    arow0 = (long)(ar0 / 31) * 32 + (ar0 % 31) + 1;
    arow1 = (long)(ar1 / 31) * 32 + (ar1 % 31) + 1;
  } else {
    arow0 = ar0; arow1 = ar1;
  }

  const u16* ga0 = A + arow0 * 1024 + (t & 3) * 8;
  const u16* ga1 = A + arow1 * 1024 + (t & 3) * 8;
  const u16* gb0 = Bt + ((long)nt * 128 + (t >> 2)) * 1024 + (t & 3) * 8;
  const u16* gb1 = gb0 + 64 * 1024;

  u16* dA0 = As + w * 512; u16* dA1 = As + 2048 + w * 512;
  u16* dB0 = Bs + w * 512; u16* dB1 = Bs + 2048 + w * 512;

  f32x4 acc[4][4] = {};

  for (int kt = 0; kt < 32; ++kt) {
    __syncthreads();
    gload_lds16(ga0, dA0); gload_lds16(ga1, dA1);
    gload_lds16(gb0, dB0); gload_lds16(gb1, dB1);
    ga0 += 32; ga1 += 32; gb0 += 32; gb1 += 32;
    __syncthreads();
    bf16x8 a[4], b[4];
#pragma unroll
    for (int m = 0; m < 4; ++m)
      a[m] = *(const bf16x8*)&As[(wr * 64 + m * 16 + lr) * 32 + lg * 8];
#pragma unroll
    for (int n = 0; n < 4; ++n)
      b[n] = *(const bf16x8*)&Bs[(wc * 64 + n * 16 + lr) * 32 + lg * 8];
#pragma unroll
    for (int m = 0; m < 4; ++m)
#pragma unroll
      for (int n = 0; n < 4; ++n)
        acc[m][n] = __builtin_amdgcn_mfma_f32_16x16x32_bf16(a[m], b[n], acc[m][n], 0, 0, 0);
  }

#pragma unroll
  for (int m = 0; m < 4; ++m) {
#pragma unroll
    for (int j = 0; j < 4; ++j) {
      int r = mt * 128 + wr * 64 + m * 16 + lg * 4 + j;
      if (r >= M) continue;
      if constexpr (MODE == 0) {
        u16* oc = (u16*)outp;
#pragma unroll
        for (int n = 0; n < 4; ++n) {
          int col = nt * 128 + wc * 64 + n * 16 + lr;
          oc[((long)r * 32 + mz) * 1024 + col] = f2bf(tanhf(acc[m][n][j]));
        }
      } else {
        int sb = r / 31, l1 = r % 31;
        int s = sb >> 6, b = sb & 63;
        int widx = xtok[b * 128 + (s + 1) * 32 + l1];
        const float* wwr = Ww + (long)widx * 1024;
        u16* oc = (u16*)outp;
#pragma unroll
        for (int n = 0; n < 4; ++n) {
          int col = nt * 128 + wc * 64 + n * 16 + lr;
          oc[(long)r * 1024 + col] = f2bf(tanhf(acc[m][n][j] + wwr[col]));
        }
      }
    }
  }
}

// ---------------- BIG GEMM: 256x256 tile, BK=64, 8-phase schedule --------
#define NOSTAGE ((void)0)
#define VM4 asm volatile("s_waitcnt vmcnt(4)" ::: "memory")
#define VM0 asm volatile("s_waitcnt vmcnt(0)" ::: "memory")

#define STAGE_A(H, KT) do {                                                \
    const u16* _s = ((H) ? pA1 : pA0) + (KT) * 64;                         \
    u16* _d = lds + ((KT) & 1) * 16384 + (H) * 8192 + w * 512;             \
    gload_lds16(_s, _d); gload_lds16(_s + 32, _d + 4096);                  \
  } while (0)
#define STAGE_B(H, KT) do {                                                \
    const u16* _s = ((H) ? pB1 : pB0) + (KT) * 64;                         \
    u16* _d = lds + 32768 + ((KT) & 1) * 16384 + (H) * 8192 + w * 512;     \
    gload_lds16(_s, _d); gload_lds16(_s + 32, _d + 4096);                  \
  } while (0)

#define PHASE(ABASE, MH, NH, RA, RB, STAGESTMT, WAITSTMT) do {             \
    if (RA) {                                                              \
      _Pragma("unroll") for (int ks = 0; ks < 2; ++ks)                     \
      _Pragma("unroll") for (int mf = 0; mf < 4; ++mf)                     \
        a[mf][ks] = *(const bf16x8*)(lds + (ABASE) + (MH) * 8192 + laneA + \
                                     ks * 4096 + mf * 128);                \
    }                                                                      \
    if (RB) {                                                              \
      _Pragma("unroll") for (int ks = 0; ks < 2; ++ks)                     \
      _Pragma("unroll") for (int nf = 0; nf < 2; ++nf)                     \
        b[NH][nf][ks] = *(const bf16x8*)(lds + 32768 + (ABASE) +           \
                                         (NH) * 8192 + laneB +             \
                                         ks * 4096 + nf * 128);            \
    }                                                                      \
    STAGESTMT;                                                             \
    __builtin_amdgcn_s_barrier();                                          \
    asm volatile("s_waitcnt lgkmcnt(0)" ::: "memory");                     \
    __builtin_amdgcn_sched_barrier(0);                                     \
    __builtin_amdgcn_s_setprio(1);                                         \
    _Pragma("unroll") for (int ks = 0; ks < 2; ++ks)                       \
    _Pragma("unroll") for (int mf = 0; mf < 4; ++mf)                       \
    _Pragma("unroll") for (int nf = 0; nf < 2; ++nf)                       \
      acc[(MH) * 4 + mf][(NH) * 2 + nf] =                                  \
          __builtin_amdgcn_mfma_f32_16x16x32_bf16(                         \
              a[mf][ks], b[NH][nf][ks],                                    \
              acc[(MH) * 4 + mf][(NH) * 2 + nf], 0, 0, 0);                 \
    __builtin_amdgcn_s_setprio(0);                                         \
    WAITSTMT;                                                              \
    __builtin_amdgcn_s_barrier();                                          \
  } while (0)

__global__ __launch_bounds__(512, 2) void gemm_big(
    const u16* __restrict__ A, const u16* __restrict__ Bt,
    float* __restrict__ out) {
  // XCD k owns mt {3k,3k+1,3k+2}: A-slab (1.5 MB) stays L2-resident;
  // nt walks slowly with 3x consecutive B-tile reuse.
  int bid = blockIdx.x;                       // 3000 = 8 * 375
  int xcd = bid & 7, idx = bid >> 3;
  int nt = idx / 3;                           // 0..124
  int mt = xcd * 3 + idx % 3;                 // 0..23

  __shared__ __align__(16) u16 lds[65536];    // A [0,32768) | B [32768,65536)

  const int t = threadIdx.x;
  const int w = t >> 6, l = t & 63;
  const int lr = l & 15, lg = l >> 4;
  const int wm = w >> 2, wn = w & 3;          // 2 x 4 waves
  const int laneA = (lg * 128 + wm * 64 + lr) * 8;
  const int laneB = (lg * 128 + wn * 32 + lr) * 8;

  int arow0 = mt * 256 + (t & 127);
  int arow1 = arow0 + 128;
  if (arow0 > 5951) arow0 = 5951;
  if (arow1 > 5951) arow1 = 5951;
  const u16* pA0 = A + (long)arow0 * 1024 + (t >> 7) * 8;
  const u16* pA1 = A + (long)arow1 * 1024 + (t >> 7) * 8;
  const u16* pB0 = Bt + ((long)nt * 256 + (t & 127)) * 1024 + (t >> 7) * 8;
  const u16* pB1 = pB0 + 128 * 1024;

  f32x4 acc[8][4] = {};
  bf16x8 a[4][2], b[2][2][2];

  // prologue: Ah0(0) Bh0(0) Bh1(0) Ah1(0) Ah0(1) Bh0(1); wait tile0; barrier
  STAGE_A(0, 0); STAGE_B(0, 0); STAGE_B(1, 0); STAGE_A(1, 0);
  STAGE_A(0, 1); STAGE_B(0, 1);
  VM4;
  __builtin_amdgcn_s_barrier();

  for (int g = 0; g < 14; g += 2) {
    PHASE(0,     0, 0, 1, 1, STAGE_B(1, g + 1), NOSTAGE);
    PHASE(0,     0, 1, 0, 1, STAGE_A(1, g + 1), NOSTAGE);
    PHASE(0,     1, 0, 1, 0, STAGE_A(0, g + 2), NOSTAGE);
    PHASE(0,     1, 1, 0, 0, STAGE_B(0, g + 2), VM4);
    PHASE(16384, 0, 0, 1, 1, STAGE_B(1, g + 2), NOSTAGE);
    PHASE(16384, 0, 1, 0, 1, STAGE_A(1, g + 2), NOSTAGE);
    PHASE(16384, 1, 0, 1, 0, STAGE_A(0, g + 3), NOSTAGE);
    PHASE(16384, 1, 1, 0, 0, STAGE_B(0, g + 3), VM4);
  }
  // group 14 (buf 0): stage tile 15's trailing halves; tile 16 doesn't exist
  PHASE(0,     0, 0, 1, 1, STAGE_B(1, 15), NOSTAGE);
  PHASE(0,     0, 1, 0, 1, STAGE_A(1, 15), NOSTAGE);
  PHASE(0,     1, 0, 1, 0, NOSTAGE, NOSTAGE);
  PHASE(0,     1, 1, 0, 0, NOSTAGE, VM0);
  // group 15 (buf 1): pure drain
  PHASE(16384, 0, 0, 1, 1, NOSTAGE, NOSTAGE);
  PHASE(16384, 0, 1, 0, 1, NOSTAGE, NOSTAGE);
  PHASE(16384, 1, 0, 1, 0, NOSTAGE, NOSTAGE);
  PHASE(16384, 1, 1, 0, 0, NOSTAGE, NOSTAGE);

  // epilogue: per-wave LDS transpose -> full 128B-line nontemporal dwordx4.
  // Wave slice: 64 rows x 33 f32 (pad 33 => <=2-way read conflicts).
  float* T = (float*)lds + w * 2112;
#pragma unroll
  for (int mh = 0; mh < 2; ++mh)
#pragma unroll
    for (int nh = 0; nh < 2; ++nh) {
#pragma unroll
      for (int mf = 0; mf < 4; ++mf)
#pragma unroll
        for (int j = 0; j < 4; ++j)
#pragma unroll
          for (int nf = 0; nf < 2; ++nf)
            T[(mf * 16 + lg * 4 + j) * 33 + nf * 16 + lr] =
                acc[mh * 4 + mf][nh * 2 + nf][j];
#pragma unroll
      for (int i = 0; i < 8; ++i) {
        int row = (l >> 3) + 8 * i;
        int c4 = (l & 7) * 4;
        f32x4 v;
        v[0] = T[row * 33 + c4];     v[1] = T[row * 33 + c4 + 1];
        v[2] = T[row * 33 + c4 + 2]; v[3] = T[row * 33 + c4 + 3];
        int r = mt * 256 + mh * 128 + wm * 64 + row;
        if (r < 5952) {
          int s = r / 1984, rem = r % 1984;
          int bb = rem / 31, l1 = rem % 31;
          float* o = out + ((long)bb * 96 + s * 32 + l1 + 1) * 32000 +
                     nt * 256 + nh * 128 + wn * 32 + c4;
          __builtin_nontemporal_store(v, (f32x4*)o);
        }
      }
    }
}

// ------------------------------- launch ---------------------------------
extern "C" void kernel_launch(void* const* d_in, const int* in_sizes, int n_in,
                              void* d_out, int out_size, void* d_ws, size_t ws_size,
                              hipStream_t stream) {
  const int*   x    = (const int*)d_in[0];
  const float* emb  = (const float*)d_in[2];
  const float* Wcsm = (const float*)d_in[3];
  const float* Wx1  = (const float*)d_in[4];
  const float* Wh1  = (const float*)d_in[5];
  const float* Wx2  = (const float*)d_in[6];
  const float* Wh2  = (const float*)d_in[7];
  const float* U    = (const float*)d_in[8];
  const float* Ww   = (const float*)d_in[9];
  const float* Wc   = (const float*)d_in[10];
  const float* Wfc  = (const float*)d_in[11];
  float* out = (float*)d_out;

  char* ws = (char*)d_ws;
  u16* sentM = (u16*)(ws + 0);          //  196608 [192][512]
  u16* sentH = (u16*)(ws + 196608);     //  393216 [192][1024]
  u16* h1a   = (u16*)(ws + 589824);     //  131072 [64][1024]
  u16* h1b   = (u16*)(ws + 720896);     //  131072
  u16* hsb   = (u16*)(ws + 851968);     //  393216 [192][1024]
  u16* ctx   = (u16*)(ws + 1245184);    // 12582912 [192*32][1024]
  u16* WcsmT = (u16*)(ws + 1245184);    //  1048576 [1024][512]   (pre-ctx)
  u16* WxhT1 = (u16*)(ws + 2293760);    //  4194304 [1024][2048]  (pre-ctx)
  u16* WxhT2 = (u16*)(ws + 6488064);    //  4194304 [1024][2048]  (pre-ctx)
  u16* cur   = (u16*)(ws + 13828096);   // 12189696 [5952][1024]
  u16* WcT   = (u16*)(ws + 26017792);   //  2097152 [1024][1024]
  u16* BIG   = (u16*)(ws + 28114944);   // 67108864 U^T then Wfc^T

  onehot_k<<<1536, 256, 0, stream>>>(x, out);

  // all six [1024][1024/512] weight transposes in one launch
  TJobs jobs;
  jobs.j[0] = {Wx1,  WxhT1,        1024, 2048};
  jobs.j[1] = {Wh1,  WxhT1 + 1024, 1024, 2048};
  jobs.j[2] = {Wx2,  WxhT2,        1024, 2048};
  jobs.j[3] = {Wh2,  WxhT2 + 1024, 1024, 2048};
  jobs.j[4] = {Wc,   WcT,          1024, 1024};
  jobs.j[5] = {Wcsm, WcsmT,         512,  512};
  transpose64_multi<<<dim3(32, 16, 6), 256, 0, stream>>>(jobs);

  // CSM: mean-pool + tanh(sentM @ Wcsm)
  meanpool_k<<<192, 256, 0, stream>>>(x, emb, sentM);
  gemm_small<<<dim3(3, 8), 256, 0, stream>>>(sentM, sentM, WcsmT, sentH, 192, 512, 512, 512, 512);

  // RNN: h = tanh([x h] @ [Wx;Wh]) via concat-K; hs[s] lands in hsb rows s*64..
  gemm_small<<<dim3(1, 8), 256, 0, stream>>>(sentH,          h1a, WxhT1, h1a,           64, 1024, 1024, 1024, 2048);
  gemm_small<<<dim3(1, 8), 256, 0, stream>>>(h1a,            h1a, WxhT2, hsb,           64, 1024, 1024, 1024, 2048);
  gemm_small<<<dim3(1, 8), 256, 0, stream>>>(sentH + 65536,  h1a, WxhT1, h1b,           64, 2048, 1024, 1024, 2048);
  gemm_small<<<dim3(1, 8), 256, 0, stream>>>(h1b,            hsb, WxhT2, hsb + 65536,   64, 2048, 1024, 1024, 2048);
  gemm_small<<<dim3(1, 8), 256, 0, stream>>>(sentH + 131072, h1b, WxhT1, h1a,           64, 2048, 1024, 1024, 2048);
  gemm_small<<<dim3(1, 8), 256, 0, stream>>>(h1a, hsb + 65536, WxhT2, hsb + 131072,     64, 2048, 1024, 1024, 2048);

  // contexts: per-m GEMM against U[m]^T
  transpose64<<<dim3(32, 16, 32), 256, 0, stream>>>(U, BIG, 1024, 1024, 1024);
  gemm_bf16<0><<<dim3(2, 8, 32), 256, 0, stream>>>(hsb, BIG, nullptr, nullptr, (void*)ctx, 192);

  // cur: GEMM against Wc^T with Ww gather + tanh epilogue
  gemm_bf16<1><<<dim3(47, 8, 1), 256, 0, stream>>>(ctx, WcT, Ww, x, (void*)cur, 5952);

  // y_sec: 8-phase 256^2 GEMM against Wfc^T (BIG reused), writes d_out
  transpose64<<<dim3(1000, 16, 1), 256, 0, stream>>>(Wfc, BIG, 1024, 32000, 1024);
  gemm_big<<<3000, 512, 0, stream>>>(cur, BIG, out);
}